// Round 3
// baseline (288.767 us; speedup 1.0000x reference)
//
#include <hip/hip_runtime.h>
#include <hip/hip_cooperative_groups.h>
#include <math.h>

namespace cg = cooperative_groups;

#define NS 4096
#define DD 768
#define NH 30          // N_HIPER
#define NCH 31         // channels per cell
#define NCELL 81       // 9x9 grid
#define NBLK 512       // blocks = chunks
#define NTHR 384       // threads per block (each owns 2 d's)
#define CS 8           // samples per chunk = NS/NBLK
#define NPART 6        // sample partitions for wacc (81*6 = 486 <= 512 blocks)
#define SPP 683        // ceil(NS/NPART)
#define NW (NCELL*DD)  // 62208 W elements

__global__ __launch_bounds__(NTHR, 3) void fused_kernel(
    const float* __restrict__ samples, const float* __restrict__ last_point,
    const float* __restrict__ emb,
    int4* __restrict__ cells, float4* __restrict__ coefs,
    float* __restrict__ chunk_sum, float* __restrict__ offs,
    float* __restrict__ w, float* __restrict__ W, float* __restrict__ out)
{
    cg::grid_group grid = cg::this_grid();
    __shared__ int4   s_cells[CS];
    __shared__ float4 s_coefs[CS];
    __shared__ float  s_dist[CS];
    __shared__ int    s_idx[SPP];
    __shared__ float  s_cf[SPP];
    __shared__ int    s_cnt;

    const int t  = threadIdx.x;
    const int b  = blockIdx.x;
    const int d0 = 2*t;

    // ---------------- P1: prep + density gather + dd + chunk sums; zero W ----
    if (t < CS) {
        const int s = b*CS + t;
        float x = samples[2*s+0], y = samples[2*s+1];
        float xs = x + 4.0f, ys = y + 4.0f;
        int fx = (int)floorf(xs), cx = (int)ceilf(xs);
        int fy = (int)floorf(ys), cy = (int)ceilf(ys);
        float dx = x - floorf(x), dy = y - floorf(y);
        float nx, ny;
        if (s == NS-1) { nx = last_point[0]; ny = last_point[1]; }
        else           { nx = samples[2*s+2]; ny = samples[2*s+3]; }
        float ex = nx - x, ey = ny - y;
        s_dist[t] = sqrtf(ex*ex + ey*ey);
        int4 cl = make_int4(fx*9+fy, cx*9+fy, fx*9+cy, cx*9+cy);
        float4 cf = make_float4((1.f-dx)*(1.f-dy), dx*(1.f-dy),
                                (1.f-dx)*dy,       dx*dy);
        s_cells[t] = cl; s_coefs[t] = cf;
        cells[s] = cl;   coefs[s] = cf;      // for P4
    }
    {   // zero W (needed before P4's atomics)
        const int g = b*NTHR + t;
        if (g < NW) W[g] = 0.f;
    }
    __syncthreads();

    float ddx[CS], ddy[CS];          // held in registers through P3
    {
        float sx = 0.f, sy = 0.f;
        #pragma unroll
        for (int i = 0; i < CS; ++i) {
            int4 cl = s_cells[i]; float4 cf = s_coefs[i]; float dist = s_dist[i];
            const int off = NH*DD + d0;
            float2 e0 = *(const float2*)(emb + cl.x*NCH*DD + off);
            float2 e1 = *(const float2*)(emb + cl.y*NCH*DD + off);
            float2 e2 = *(const float2*)(emb + cl.z*NCH*DD + off);
            float2 e3 = *(const float2*)(emb + cl.w*NCH*DD + off);
            float vx = e0.x*cf.x + e1.x*cf.y + e2.x*cf.z + e3.x*cf.w;
            float vy = e0.y*cf.x + e1.y*cf.y + e2.y*cf.z + e3.y*cf.w;
            ddx[i] = fmaxf(vx, 0.f) * dist;
            ddy[i] = fmaxf(vy, 0.f) * dist;
            sx += ddx[i]; sy += ddy[i];
        }
        *(float2*)(chunk_sum + b*DD + d0) = make_float2(sx, sy);
    }
    grid.sync();

    // ---------------- P2: exclusive scan over 512 chunks per d (768 waves) ---
    {
        const int gw   = b*(NTHR/64) + (t >> 6);   // global wave id
        const int lane = t & 63;
        if (gw < DD) {
            const int d = gw;
            float v[8];
            #pragma unroll
            for (int k = 0; k < 8; ++k)
                v[k] = chunk_sum[(lane*8 + k)*DD + d];
            float tot = 0.f;
            #pragma unroll
            for (int k = 0; k < 8; ++k) tot += v[k];
            float x = tot;
            #pragma unroll
            for (int off = 1; off < 64; off <<= 1) {
                float y = __shfl_up(x, off);
                if (lane >= off) x += y;
            }
            float run = x - tot;    // exclusive prefix of this lane's group
            #pragma unroll
            for (int k = 0; k < 8; ++k) {
                offs[(lane*8 + k)*DD + d] = run;
                run += v[k];
            }
        }
    }
    grid.sync();

    // ---------------- P3: w[s,d] from register dd + offs ---------------------
    {
        float2 cum = *(const float2*)(offs + b*DD + d0);
        #pragma unroll
        for (int i = 0; i < CS; ++i) {
            float wx = __expf(-cum.x) * (1.f - __expf(-ddx[i]));
            float wy = __expf(-cum.y) * (1.f - __expf(-ddy[i]));
            *(float2*)(w + (b*CS + i)*DD + d0) = make_float2(wx, wy);
            cum.x += ddx[i];
            cum.y += ddy[i];
        }
    }
    grid.sync();

    // ---------------- P4: W[g,d] accumulation (cell-major, LDS match list) ---
    if (b < NCELL*NPART) {
        const int g    = b / NPART;
        const int part = b % NPART;
        if (t == 0) s_cnt = 0;
        __syncthreads();
        const int s_beg = part*SPP;
        const int s_end = min(NS, s_beg + SPP);
        for (int s = s_beg + t; s < s_end; s += NTHR) {
            int4 cl = cells[s]; float4 cf = coefs[s];
            float c = 0.f;
            if (cl.x == g) c += cf.x;
            if (cl.y == g) c += cf.y;
            if (cl.z == g) c += cf.z;
            if (cl.w == g) c += cf.w;
            if (c != 0.f) {
                int idx = atomicAdd(&s_cnt, 1);
                s_idx[idx] = s;
                s_cf[idx]  = c;
            }
        }
        __syncthreads();
        const int cnt = s_cnt;
        float a0 = 0.f, a1 = 0.f;
        for (int j = 0; j < cnt; ++j) {
            const float* wr = w + s_idx[j]*DD;
            const float  c  = s_cf[j];
            a0 += c * wr[t];
            a1 += c * wr[t + NTHR];
        }
        atomicAdd(&W[g*DD + t       ], a0);
        atomicAdd(&W[g*DD + t + NTHR], a1);
    }
    grid.sync();

    // ---------------- P5: out[n,d] = sum_g W[g,d] * T[g,n,d] -----------------
    if (b < NH) {
        const int n = b;
        float ax = 0.f, ay = 0.f;
        #pragma unroll 3
        for (int g = 0; g < NCELL; ++g) {
            float2 Wv = *(const float2*)(W + g*DD + d0);
            float2 Tv = *(const float2*)(emb + (g*NCH + n)*DD + d0);
            ax += Wv.x*Tv.x;
            ay += Wv.y*Tv.y;
        }
        *(float2*)(out + n*DD + d0) = make_float2(ax, ay);
    }
}

// ---------------------------------------------------------------------------
extern "C" void kernel_launch(void* const* d_in, const int* in_sizes, int n_in,
                              void* d_out, int out_size, void* d_ws, size_t ws_size,
                              hipStream_t stream) {
    const float* samples    = (const float*)d_in[0];
    const float* last_point = (const float*)d_in[1];
    const float* emb        = (const float*)d_in[2];
    float* out = (float*)d_out;

    char* ws = (char*)d_ws;
    int4*   cells = (int4*)ws;      ws += (size_t)NS*sizeof(int4);
    float4* coefs = (float4*)ws;    ws += (size_t)NS*sizeof(float4);
    float*  chunk_sum = (float*)ws; ws += (size_t)NBLK*DD*sizeof(float);
    float*  offs  = (float*)ws;     ws += (size_t)NBLK*DD*sizeof(float);
    float*  Wbuf  = (float*)ws;     ws += (size_t)NW*sizeof(float);
    float*  wmat  = (float*)ws;     ws += (size_t)NS*DD*sizeof(float);

    void* args[] = {
        (void*)&samples, (void*)&last_point, (void*)&emb,
        (void*)&cells, (void*)&coefs, (void*)&chunk_sum, (void*)&offs,
        (void*)&wmat, (void*)&Wbuf, (void*)&out
    };
    hipLaunchCooperativeKernel((const void*)fused_kernel,
                               dim3(NBLK), dim3(NTHR), args, 0, stream);
}

// Round 4
// 189.951 us; speedup vs baseline: 1.5202x; 1.5202x over previous
//
#include <hip/hip_runtime.h>
#include <math.h>

#define NS 4096
#define DD 768
#define NH 30          // N_HIPER
#define NCH 31         // channels per cell
#define NCELL 81       // 9x9 grid
#define NBLK 256       // chunk blocks
#define NTHR 384       // threads (each owns 2 d's)
#define CS 16          // samples per chunk = NS/NBLK
#define NPART 6        // sample partitions for wacc
#define SPP 683        // ceil(NS/NPART)
#define NW (NCELL*DD)

__device__ __forceinline__ float ldA(const float* p) {
    return __hip_atomic_load(p, __ATOMIC_RELAXED, __HIP_MEMORY_SCOPE_AGENT);
}

// ---------------------------------------------------------------------------
// scanw: prep + density gather + dd (regs) + decoupled-lookback chunk scan +
//        w materialization. Also zeroes W and writes cells/coefs.
// ---------------------------------------------------------------------------
__global__ __launch_bounds__(NTHR) void scanw_kernel(
    const float* __restrict__ samples, const float* __restrict__ last_point,
    const float* __restrict__ emb,
    int4* __restrict__ cells, float4* __restrict__ coefs,
    float* __restrict__ aggbuf, float* __restrict__ inclbuf,
    int* __restrict__ flags,
    float* __restrict__ w, float* __restrict__ W)
{
    __shared__ int4   s_cells[CS];
    __shared__ float4 s_coefs[CS];
    __shared__ float  s_dist[CS];
    __shared__ int    s_flag;

    const int t  = threadIdx.x;
    const int b  = blockIdx.x;
    const int d0 = 2*t;

    // ---- prep (16 samples) + zero W ----------------------------------------
    if (t < CS) {
        const int s = b*CS + t;
        float x = samples[2*s+0], y = samples[2*s+1];
        float xs = x + 4.0f, ys = y + 4.0f;
        int fx = (int)floorf(xs), cx = (int)ceilf(xs);
        int fy = (int)floorf(ys), cy = (int)ceilf(ys);
        float dx = x - floorf(x), dy = y - floorf(y);
        float nx, ny;
        if (s == NS-1) { nx = last_point[0]; ny = last_point[1]; }
        else           { nx = samples[2*s+2]; ny = samples[2*s+3]; }
        float ex = nx - x, ey = ny - y;
        s_dist[t] = sqrtf(ex*ex + ey*ey);
        int4 cl = make_int4(fx*9+fy, cx*9+fy, fx*9+cy, cx*9+cy);
        float4 cf = make_float4((1.f-dx)*(1.f-dy), dx*(1.f-dy),
                                (1.f-dx)*dy,       dx*dy);
        s_cells[t] = cl; s_coefs[t] = cf;
        cells[s] = cl;   coefs[s]  = cf;     // for wacc
    }
    { int g = b*NTHR + t; if (g < NW) W[g] = 0.f; }
    __syncthreads();

    // ---- density gather, dd in registers, block aggregate ------------------
    float2 dd[CS];
    float2 agg = make_float2(0.f, 0.f);
    #pragma unroll
    for (int i = 0; i < CS; ++i) {
        int4 cl = s_cells[i]; float4 cf = s_coefs[i]; float dist = s_dist[i];
        const int off = NH*DD + d0;
        float2 e0 = *(const float2*)(emb + cl.x*NCH*DD + off);
        float2 e1 = *(const float2*)(emb + cl.y*NCH*DD + off);
        float2 e2 = *(const float2*)(emb + cl.z*NCH*DD + off);
        float2 e3 = *(const float2*)(emb + cl.w*NCH*DD + off);
        float vx = e0.x*cf.x + e1.x*cf.y + e2.x*cf.z + e3.x*cf.w;
        float vy = e0.y*cf.x + e1.y*cf.y + e2.y*cf.z + e3.y*cf.w;
        dd[i].x = fmaxf(vx, 0.f) * dist;
        dd[i].y = fmaxf(vy, 0.f) * dist;
        agg.x += dd[i].x; agg.y += dd[i].y;
    }

    // ---- publish aggregate (flag=1) ----------------------------------------
    if (b > 0) {
        *(float2*)(aggbuf + b*DD + d0) = agg;
        __threadfence();
        __syncthreads();
        if (t == 0)
            __hip_atomic_store(&flags[b], 1, __ATOMIC_RELEASE,
                               __HIP_MEMORY_SCOPE_AGENT);
    }

    // ---- decoupled lookback -------------------------------------------------
    float2 run = make_float2(0.f, 0.f);
    if (b > 0) {
        int prev = b - 1;
        for (;;) {
            if (t == 0) {
                int f;
                do {
                    f = __hip_atomic_load(&flags[prev], __ATOMIC_ACQUIRE,
                                          __HIP_MEMORY_SCOPE_AGENT);
                    if (f == 0) __builtin_amdgcn_s_sleep(2);
                } while (f == 0);
                s_flag = f;
            }
            __syncthreads();
            const int f = s_flag;
            const float* src = (f == 2 ? inclbuf : aggbuf) + prev*DD;
            run.x += ldA(src + d0);
            run.y += ldA(src + d0 + 1);
            __syncthreads();
            if (f == 2) break;
            --prev;
        }
    }

    // ---- publish inclusive (flag=2) ----------------------------------------
    *(float2*)(inclbuf + b*DD + d0) = make_float2(run.x + agg.x, run.y + agg.y);
    __threadfence();
    __syncthreads();
    if (t == 0)
        __hip_atomic_store(&flags[b], 2, __ATOMIC_RELEASE,
                           __HIP_MEMORY_SCOPE_AGENT);

    // ---- w from register dd (telescoping: one exp per element) -------------
    float Ex = __expf(-run.x), Ey = __expf(-run.y);
    #pragma unroll
    for (int i = 0; i < CS; ++i) {
        float fx = __expf(-dd[i].x), fy = __expf(-dd[i].y);
        *(float2*)(w + (b*CS + i)*DD + d0) =
            make_float2(Ex * (1.f - fx), Ey * (1.f - fy));
        Ex *= fx; Ey *= fy;
    }
}

// ---------------------------------------------------------------------------
// wacc: W[g,d] += sum over samples with corner g of coef*w[s,d]
// ---------------------------------------------------------------------------
__global__ __launch_bounds__(256) void wacc_kernel(
    const int4* __restrict__ cells, const float4* __restrict__ coefs,
    const float* __restrict__ w, float* __restrict__ W) {
    __shared__ int   s_idx[SPP];
    __shared__ float s_cf[SPP];
    __shared__ int   s_cnt;
    const int g    = blockIdx.x / NPART;
    const int part = blockIdx.x % NPART;
    const int t    = threadIdx.x;
    if (t == 0) s_cnt = 0;
    __syncthreads();
    const int s_beg = part * SPP;
    const int s_end = min(NS, s_beg + SPP);
    for (int s = s_beg + t; s < s_end; s += 256) {
        int4 cl = cells[s]; float4 cf = coefs[s];
        float c = 0.f;
        if (cl.x == g) c += cf.x;
        if (cl.y == g) c += cf.y;
        if (cl.z == g) c += cf.z;
        if (cl.w == g) c += cf.w;
        if (c != 0.f) {
            int idx = atomicAdd(&s_cnt, 1);
            s_idx[idx] = s;
            s_cf[idx]  = c;
        }
    }
    __syncthreads();
    const int cnt = s_cnt;
    float a0 = 0.f, a1 = 0.f, a2 = 0.f;
    for (int j = 0; j < cnt; ++j) {
        const float* wr = w + (long)s_idx[j]*DD;
        const float  c  = s_cf[j];
        a0 += c * wr[t];
        a1 += c * wr[t + 256];
        a2 += c * wr[t + 512];
    }
    atomicAdd(&W[g*DD + t      ], a0);
    atomicAdd(&W[g*DD + t + 256], a1);
    atomicAdd(&W[g*DD + t + 512], a2);
}

// ---------------------------------------------------------------------------
// final: out[n,d] = sum_g W[g,d] * T[g,n,d]
// ---------------------------------------------------------------------------
__global__ __launch_bounds__(256) void final_kernel(
    const float* __restrict__ emb, const float* __restrict__ W,
    float* __restrict__ out) {
    const int n    = blockIdx.x / 3;
    const int part = blockIdx.x % 3;
    const int d    = part*256 + threadIdx.x;
    float a0 = 0.f, a1 = 0.f, a2 = 0.f, a3 = 0.f;
    int g = 0;
    #pragma unroll 4
    for (; g + 4 <= 80; g += 4) {
        a0 += W[(g+0)*DD + d] * emb[((g+0)*NCH + n)*DD + d];
        a1 += W[(g+1)*DD + d] * emb[((g+1)*NCH + n)*DD + d];
        a2 += W[(g+2)*DD + d] * emb[((g+2)*NCH + n)*DD + d];
        a3 += W[(g+3)*DD + d] * emb[((g+3)*NCH + n)*DD + d];
    }
    a0 += W[80*DD + d] * emb[(80*NCH + n)*DD + d];
    out[n*DD + d] = (a0 + a1) + (a2 + a3);
}

// ---------------------------------------------------------------------------
extern "C" void kernel_launch(void* const* d_in, const int* in_sizes, int n_in,
                              void* d_out, int out_size, void* d_ws, size_t ws_size,
                              hipStream_t stream) {
    const float* samples    = (const float*)d_in[0];
    const float* last_point = (const float*)d_in[1];
    const float* emb        = (const float*)d_in[2];
    float* out = (float*)d_out;

    char* ws = (char*)d_ws;
    int4*   cells  = (int4*)ws;    ws += (size_t)NS*sizeof(int4);
    float4* coefs  = (float4*)ws;  ws += (size_t)NS*sizeof(float4);
    float*  aggbuf = (float*)ws;   ws += (size_t)NBLK*DD*sizeof(float);
    float*  inclbuf= (float*)ws;   ws += (size_t)NBLK*DD*sizeof(float);
    int*    flags  = (int*)ws;     ws += (size_t)NBLK*sizeof(int);
    float*  Wbuf   = (float*)ws;   ws += (size_t)NW*sizeof(float);
    float*  wmat   = (float*)ws;   ws += (size_t)NS*DD*sizeof(float);

    hipMemsetAsync(flags, 0, NBLK*sizeof(int), stream);
    scanw_kernel<<<NBLK, NTHR, 0, stream>>>(samples, last_point, emb,
                                            cells, coefs, aggbuf, inclbuf,
                                            flags, wmat, Wbuf);
    wacc_kernel<<<NCELL*NPART, 256, 0, stream>>>(cells, coefs, wmat, Wbuf);
    final_kernel<<<NH*3, 256, 0, stream>>>(emb, Wbuf, out);
}

// Round 5
// 167.437 us; speedup vs baseline: 1.7246x; 1.1345x over previous
//
#include <hip/hip_runtime.h>
#include <math.h>

#define NS 4096
#define DD 768
#define NH 30          // N_HIPER
#define NCH 31         // channels per cell
#define NCELL 81       // 9x9 grid
#define NBLK 256       // chunk blocks
#define NTHR 384       // threads (each owns 2 d's)
#define CS 16          // samples per chunk = NS/NBLK
#define NPART 6        // sample partitions for wacc
#define SPP 683        // ceil(NS/NPART)
#define NW (NCELL*DD)
#define NACC (NCELL*NPART)   // 486 wacc blocks

__device__ __forceinline__ float ldA(const float* p) {
    return __hip_atomic_load(p, __ATOMIC_RELAXED, __HIP_MEMORY_SCOPE_AGENT);
}

// ---------------------------------------------------------------------------
// scanw: prep + density gather + dd (regs) + PARALLEL all-predecessor chunk
//        scan + w materialization. Also zeroes W and writes cells/coefs.
// ---------------------------------------------------------------------------
__global__ __launch_bounds__(NTHR) void scanw_kernel(
    const float* __restrict__ samples, const float* __restrict__ last_point,
    const float* __restrict__ emb,
    int4* __restrict__ cells, float4* __restrict__ coefs,
    float* __restrict__ aggbuf, int* __restrict__ flags,
    float* __restrict__ w, float* __restrict__ W)
{
    __shared__ int4   s_cells[CS];
    __shared__ float4 s_coefs[CS];
    __shared__ float  s_dist[CS];

    const int t  = threadIdx.x;
    const int b  = blockIdx.x;
    const int d0 = 2*t;

    // ---- prep (16 samples) + zero W ----------------------------------------
    if (t < CS) {
        const int s = b*CS + t;
        float x = samples[2*s+0], y = samples[2*s+1];
        float xs = x + 4.0f, ys = y + 4.0f;
        int fx = (int)floorf(xs), cx = (int)ceilf(xs);
        int fy = (int)floorf(ys), cy = (int)ceilf(ys);
        float dx = x - floorf(x), dy = y - floorf(y);
        float nx, ny;
        if (s == NS-1) { nx = last_point[0]; ny = last_point[1]; }
        else           { nx = samples[2*s+2]; ny = samples[2*s+3]; }
        float ex = nx - x, ey = ny - y;
        s_dist[t] = sqrtf(ex*ex + ey*ey);
        int4 cl = make_int4(fx*9+fy, cx*9+fy, fx*9+cy, cx*9+cy);
        float4 cf = make_float4((1.f-dx)*(1.f-dy), dx*(1.f-dy),
                                (1.f-dx)*dy,       dx*dy);
        s_cells[t] = cl; s_coefs[t] = cf;
        cells[s] = cl;   coefs[s]  = cf;     // for wacc
    }
    { int g = b*NTHR + t; if (g < NW) W[g] = 0.f; }
    __syncthreads();

    // ---- density gather, dd in registers, block aggregate ------------------
    float2 dd[CS];
    float2 agg = make_float2(0.f, 0.f);
    #pragma unroll
    for (int i = 0; i < CS; ++i) {
        int4 cl = s_cells[i]; float4 cf = s_coefs[i]; float dist = s_dist[i];
        const int off = NH*DD + d0;
        float2 e0 = *(const float2*)(emb + cl.x*NCH*DD + off);
        float2 e1 = *(const float2*)(emb + cl.y*NCH*DD + off);
        float2 e2 = *(const float2*)(emb + cl.z*NCH*DD + off);
        float2 e3 = *(const float2*)(emb + cl.w*NCH*DD + off);
        float vx = e0.x*cf.x + e1.x*cf.y + e2.x*cf.z + e3.x*cf.w;
        float vy = e0.y*cf.x + e1.y*cf.y + e2.y*cf.z + e3.y*cf.w;
        dd[i].x = fmaxf(vx, 0.f) * dist;
        dd[i].y = fmaxf(vy, 0.f) * dist;
        agg.x += dd[i].x; agg.y += dd[i].y;
    }

    // ---- publish aggregate (flag=1), all blocks ----------------------------
    *(float2*)(aggbuf + b*DD + d0) = agg;
    __threadfence();
    __syncthreads();
    if (t == 0)
        __hip_atomic_store(&flags[b], 1, __ATOMIC_RELEASE,
                           __HIP_MEMORY_SCOPE_AGENT);

    // ---- wait for ALL predecessors (lane-parallel poll, no chain) ----------
    for (int p = t; p < b; p += NTHR) {
        while (__hip_atomic_load(&flags[p], __ATOMIC_ACQUIRE,
                                 __HIP_MEMORY_SCOPE_AGENT) != 1)
            __builtin_amdgcn_s_sleep(1);
    }
    __syncthreads();

    // ---- exclusive prefix = sum of all predecessor aggregates --------------
    float2 run = make_float2(0.f, 0.f);
    {
        int p = 0;
        float ax0=0.f, ay0=0.f, ax1=0.f, ay1=0.f;
        for (; p + 4 <= b; p += 4) {
            const float* r0 = aggbuf + (p+0)*DD + d0;
            const float* r1 = aggbuf + (p+1)*DD + d0;
            const float* r2 = aggbuf + (p+2)*DD + d0;
            const float* r3 = aggbuf + (p+3)*DD + d0;
            ax0 += ldA(r0);   ay0 += ldA(r0+1);
            ax1 += ldA(r1);   ay1 += ldA(r1+1);
            ax0 += ldA(r2);   ay0 += ldA(r2+1);
            ax1 += ldA(r3);   ay1 += ldA(r3+1);
        }
        for (; p < b; ++p) {
            const float* r = aggbuf + p*DD + d0;
            ax0 += ldA(r); ay0 += ldA(r+1);
        }
        run.x = ax0 + ax1; run.y = ay0 + ay1;
    }

    // ---- w from register dd (telescoping: one exp per element) -------------
    float Ex = __expf(-run.x), Ey = __expf(-run.y);
    #pragma unroll
    for (int i = 0; i < CS; ++i) {
        float fx = __expf(-dd[i].x), fy = __expf(-dd[i].y);
        *(float2*)(w + (b*CS + i)*DD + d0) =
            make_float2(Ex * (1.f - fx), Ey * (1.f - fy));
        Ex *= fx; Ey *= fy;
    }
}

// ---------------------------------------------------------------------------
// waccfinal: W[g,d] accumulation (486 blocks) + completion counter +
//            first 90 blocks compute out[n,d] = sum_g W[g,d]*T[g,n,d]
// ---------------------------------------------------------------------------
__global__ __launch_bounds__(256) void waccfinal_kernel(
    const int4* __restrict__ cells, const float4* __restrict__ coefs,
    const float* __restrict__ w, const float* __restrict__ emb,
    float* __restrict__ W, int* __restrict__ done,
    float* __restrict__ out)
{
    __shared__ int   s_idx[SPP];
    __shared__ float s_cf[SPP];
    __shared__ int   s_cnt;
    const int b = blockIdx.x;
    const int t = threadIdx.x;

    // ---- wacc part ---------------------------------------------------------
    {
        const int g    = b / NPART;
        const int part = b % NPART;
        if (t == 0) s_cnt = 0;
        __syncthreads();
        const int s_beg = part * SPP;
        const int s_end = min(NS, s_beg + SPP);
        for (int s = s_beg + t; s < s_end; s += 256) {
            int4 cl = cells[s]; float4 cf = coefs[s];
            float c = 0.f;
            if (cl.x == g) c += cf.x;
            if (cl.y == g) c += cf.y;
            if (cl.z == g) c += cf.z;
            if (cl.w == g) c += cf.w;
            if (c != 0.f) {
                int idx = atomicAdd(&s_cnt, 1);
                s_idx[idx] = s;
                s_cf[idx]  = c;
            }
        }
        __syncthreads();
        const int cnt = s_cnt;
        float a0 = 0.f, a1 = 0.f, a2 = 0.f;
        for (int j = 0; j < cnt; ++j) {
            const float* wr = w + (long)s_idx[j]*DD;
            const float  c  = s_cf[j];
            a0 += c * wr[t];
            a1 += c * wr[t + 256];
            a2 += c * wr[t + 512];
        }
        atomicAdd(&W[g*DD + t      ], a0);
        atomicAdd(&W[g*DD + t + 256], a1);
        atomicAdd(&W[g*DD + t + 512], a2);
    }
    __threadfence();
    __syncthreads();
    if (t == 0)
        __hip_atomic_fetch_add(done, 1, __ATOMIC_ACQ_REL,
                               __HIP_MEMORY_SCOPE_AGENT);

    // ---- final part (first NH*3 = 90 blocks) -------------------------------
    if (b < NH*3) {
        if (t == 0) {
            while (__hip_atomic_load(done, __ATOMIC_ACQUIRE,
                                     __HIP_MEMORY_SCOPE_AGENT) != NACC)
                __builtin_amdgcn_s_sleep(1);
        }
        __syncthreads();
        const int n    = b / 3;
        const int part = b % 3;
        const int d    = part*256 + t;
        float a0 = 0.f, a1 = 0.f, a2 = 0.f, a3 = 0.f;
        int g = 0;
        #pragma unroll 4
        for (; g + 4 <= 80; g += 4) {
            a0 += ldA(&W[(g+0)*DD + d]) * emb[((g+0)*NCH + n)*DD + d];
            a1 += ldA(&W[(g+1)*DD + d]) * emb[((g+1)*NCH + n)*DD + d];
            a2 += ldA(&W[(g+2)*DD + d]) * emb[((g+2)*NCH + n)*DD + d];
            a3 += ldA(&W[(g+3)*DD + d]) * emb[((g+3)*NCH + n)*DD + d];
        }
        a0 += ldA(&W[80*DD + d]) * emb[(80*NCH + n)*DD + d];
        out[n*DD + d] = (a0 + a1) + (a2 + a3);
    }
}

// ---------------------------------------------------------------------------
extern "C" void kernel_launch(void* const* d_in, const int* in_sizes, int n_in,
                              void* d_out, int out_size, void* d_ws, size_t ws_size,
                              hipStream_t stream) {
    const float* samples    = (const float*)d_in[0];
    const float* last_point = (const float*)d_in[1];
    const float* emb        = (const float*)d_in[2];
    float* out = (float*)d_out;

    char* ws = (char*)d_ws;
    int4*   cells  = (int4*)ws;    ws += (size_t)NS*sizeof(int4);
    float4* coefs  = (float4*)ws;  ws += (size_t)NS*sizeof(float4);
    float*  aggbuf = (float*)ws;   ws += (size_t)NBLK*DD*sizeof(float);
    int*    flags  = (int*)ws;     ws += (size_t)NBLK*sizeof(int);
    int*    done   = (int*)ws;     ws += 4*sizeof(int);
    float*  Wbuf   = (float*)ws;   ws += (size_t)NW*sizeof(float);
    float*  wmat   = (float*)ws;   ws += (size_t)NS*DD*sizeof(float);

    // re-arm sync state every call (graph replays don't re-poison)
    hipMemsetAsync(flags, 0, (NBLK + 4)*sizeof(int), stream);
    scanw_kernel<<<NBLK, NTHR, 0, stream>>>(samples, last_point, emb,
                                            cells, coefs, aggbuf, flags,
                                            wmat, Wbuf);
    waccfinal_kernel<<<NACC, 256, 0, stream>>>(cells, coefs, wmat, emb,
                                               Wbuf, done, out);
}

// Round 6
// 38.075 us; speedup vs baseline: 7.5842x; 4.3976x over previous
//
#include <hip/hip_runtime.h>
#include <math.h>

#define NS 4096
#define DD 768
#define NH 30          // N_HIPER
#define NCH 31         // channels per cell
#define NCELL 81       // 9x9 grid
#define NBLK 256       // chunk blocks
#define NTHR 384       // threads (each owns 2 d's)
#define CS 16          // samples per chunk = NS/NBLK
#define NPART 6        // sample partitions for wacc
#define SPP 683        // ceil(NS/NPART)
#define NW (NCELL*DD)
#define NACC (NCELL*NPART)   // 486 wacc blocks

// ---------------------------------------------------------------------------
// k1 pass1: prep (fused) + density gather + dd -> global + chunk sums.
//           Also zeroes W (read later by wacc via stream-ordered dispatch)
//           and writes cells/coefs for wacc.
// ---------------------------------------------------------------------------
__global__ __launch_bounds__(NTHR) void pass1_kernel(
    const float* __restrict__ samples, const float* __restrict__ last_point,
    const float* __restrict__ emb,
    int4* __restrict__ cells, float4* __restrict__ coefs,
    float* __restrict__ ddbuf, float* __restrict__ chunk_sum,
    float* __restrict__ W)
{
    __shared__ int4   s_cells[CS];
    __shared__ float4 s_coefs[CS];
    __shared__ float  s_dist[CS];

    const int t  = threadIdx.x;
    const int b  = blockIdx.x;
    const int d0 = 2*t;

    if (t < CS) {
        const int s = b*CS + t;
        float x = samples[2*s+0], y = samples[2*s+1];
        float xs = x + 4.0f, ys = y + 4.0f;
        int fx = (int)floorf(xs), cx = (int)ceilf(xs);
        int fy = (int)floorf(ys), cy = (int)ceilf(ys);
        float dx = x - floorf(x), dy = y - floorf(y);
        float nx, ny;
        if (s == NS-1) { nx = last_point[0]; ny = last_point[1]; }
        else           { nx = samples[2*s+2]; ny = samples[2*s+3]; }
        float ex = nx - x, ey = ny - y;
        s_dist[t] = sqrtf(ex*ex + ey*ey);
        int4 cl = make_int4(fx*9+fy, cx*9+fy, fx*9+cy, cx*9+cy);
        float4 cf = make_float4((1.f-dx)*(1.f-dy), dx*(1.f-dy),
                                (1.f-dx)*dy,       dx*dy);
        s_cells[t] = cl; s_coefs[t] = cf;
        cells[s] = cl;   coefs[s]  = cf;     // for wacc
    }
    { int g = b*NTHR + t; if (g < NW) W[g] = 0.f; }   // zero W, no memset
    __syncthreads();

    float sx = 0.f, sy = 0.f;
    #pragma unroll
    for (int i = 0; i < CS; ++i) {
        int4 cl = s_cells[i]; float4 cf = s_coefs[i]; float dist = s_dist[i];
        const int off = NH*DD + d0;
        float2 e0 = *(const float2*)(emb + cl.x*NCH*DD + off);
        float2 e1 = *(const float2*)(emb + cl.y*NCH*DD + off);
        float2 e2 = *(const float2*)(emb + cl.z*NCH*DD + off);
        float2 e3 = *(const float2*)(emb + cl.w*NCH*DD + off);
        float vx = e0.x*cf.x + e1.x*cf.y + e2.x*cf.z + e3.x*cf.w;
        float vy = e0.y*cf.x + e1.y*cf.y + e2.y*cf.z + e3.y*cf.w;
        float ddx = fmaxf(vx, 0.f) * dist;
        float ddy = fmaxf(vy, 0.f) * dist;
        *(float2*)(ddbuf + (b*CS + i)*DD + d0) = make_float2(ddx, ddy);
        sx += ddx; sy += ddy;
    }
    *(float2*)(chunk_sum + b*DD + d0) = make_float2(sx, sy);
}

// ---------------------------------------------------------------------------
// k2 scan: exclusive prefix over 256 chunks per d; one wave per d
// ---------------------------------------------------------------------------
__global__ __launch_bounds__(64) void scan_kernel(
    const float* __restrict__ chunk_sum, float* __restrict__ offs) {
    const int d    = blockIdx.x;       // 0..767
    const int lane = threadIdx.x;      // 0..63
    float v[4];
    #pragma unroll
    for (int k = 0; k < 4; ++k)
        v[k] = chunk_sum[(lane*4 + k)*DD + d];
    float tot = (v[0] + v[1]) + (v[2] + v[3]);
    float x = tot;
    #pragma unroll
    for (int off = 1; off < 64; off <<= 1) {
        float y = __shfl_up(x, off);
        if (lane >= off) x += y;
    }
    float run = x - tot;   // exclusive prefix of this lane's group
    #pragma unroll
    for (int k = 0; k < 4; ++k) {
        offs[(lane*4 + k)*DD + d] = run;
        run += v[k];
    }
}

// ---------------------------------------------------------------------------
// k3 w: w[s,d] = exp(-cum_excl)*(1-exp(-dd)), telescoping (1 exp per elem)
// ---------------------------------------------------------------------------
__global__ __launch_bounds__(NTHR) void w_kernel(
    const float* __restrict__ ddbuf, const float* __restrict__ offs,
    float* __restrict__ w) {
    const int t  = threadIdx.x;
    const int b  = blockIdx.x;
    const int d0 = 2*t;
    float2 cum = *(const float2*)(offs + b*DD + d0);
    float Ex = __expf(-cum.x), Ey = __expf(-cum.y);
    #pragma unroll
    for (int i = 0; i < CS; ++i) {
        float2 dd = *(const float2*)(ddbuf + (b*CS + i)*DD + d0);
        float fx = __expf(-dd.x), fy = __expf(-dd.y);
        *(float2*)(w + (b*CS + i)*DD + d0) =
            make_float2(Ex * (1.f - fx), Ey * (1.f - fy));
        Ex *= fx; Ey *= fy;
    }
}

// ---------------------------------------------------------------------------
// k4 wacc: W[g,d] += sum over samples with corner g of coef*w[s,d]
// ---------------------------------------------------------------------------
__global__ __launch_bounds__(256) void wacc_kernel(
    const int4* __restrict__ cells, const float4* __restrict__ coefs,
    const float* __restrict__ w, float* __restrict__ W) {
    __shared__ int   s_idx[SPP];
    __shared__ float s_cf[SPP];
    __shared__ int   s_cnt;
    const int g    = blockIdx.x / NPART;
    const int part = blockIdx.x % NPART;
    const int t    = threadIdx.x;
    if (t == 0) s_cnt = 0;
    __syncthreads();
    const int s_beg = part * SPP;
    const int s_end = min(NS, s_beg + SPP);
    for (int s = s_beg + t; s < s_end; s += 256) {
        int4 cl = cells[s]; float4 cf = coefs[s];
        float c = 0.f;
        if (cl.x == g) c += cf.x;
        if (cl.y == g) c += cf.y;
        if (cl.z == g) c += cf.z;
        if (cl.w == g) c += cf.w;
        if (c != 0.f) {
            int idx = atomicAdd(&s_cnt, 1);
            s_idx[idx] = s;
            s_cf[idx]  = c;
        }
    }
    __syncthreads();
    const int cnt = s_cnt;
    float a0 = 0.f, a1 = 0.f, a2 = 0.f;
    for (int j = 0; j < cnt; ++j) {
        const float* wr = w + (long)s_idx[j]*DD;
        const float  c  = s_cf[j];
        a0 += c * wr[t];
        a1 += c * wr[t + 256];
        a2 += c * wr[t + 512];
    }
    atomicAdd(&W[g*DD + t      ], a0);
    atomicAdd(&W[g*DD + t + 256], a1);
    atomicAdd(&W[g*DD + t + 512], a2);
}

// ---------------------------------------------------------------------------
// k5 final: out[n,d] = sum_g W[g,d] * T[g,n,d]
// ---------------------------------------------------------------------------
__global__ __launch_bounds__(256) void final_kernel(
    const float* __restrict__ emb, const float* __restrict__ W,
    float* __restrict__ out) {
    const int n    = blockIdx.x / 3;
    const int part = blockIdx.x % 3;
    const int d    = part*256 + threadIdx.x;
    float a0 = 0.f, a1 = 0.f, a2 = 0.f, a3 = 0.f;
    int g = 0;
    #pragma unroll 4
    for (; g + 4 <= 80; g += 4) {
        a0 += W[(g+0)*DD + d] * emb[((g+0)*NCH + n)*DD + d];
        a1 += W[(g+1)*DD + d] * emb[((g+1)*NCH + n)*DD + d];
        a2 += W[(g+2)*DD + d] * emb[((g+2)*NCH + n)*DD + d];
        a3 += W[(g+3)*DD + d] * emb[((g+3)*NCH + n)*DD + d];
    }
    a0 += W[80*DD + d] * emb[(80*NCH + n)*DD + d];
    out[n*DD + d] = (a0 + a1) + (a2 + a3);
}

// ---------------------------------------------------------------------------
extern "C" void kernel_launch(void* const* d_in, const int* in_sizes, int n_in,
                              void* d_out, int out_size, void* d_ws, size_t ws_size,
                              hipStream_t stream) {
    const float* samples    = (const float*)d_in[0];
    const float* last_point = (const float*)d_in[1];
    const float* emb        = (const float*)d_in[2];
    float* out = (float*)d_out;

    char* ws = (char*)d_ws;
    int4*   cells  = (int4*)ws;     ws += (size_t)NS*sizeof(int4);
    float4* coefs  = (float4*)ws;   ws += (size_t)NS*sizeof(float4);
    float*  chunk_sum = (float*)ws; ws += (size_t)NBLK*DD*sizeof(float);
    float*  offs   = (float*)ws;    ws += (size_t)NBLK*DD*sizeof(float);
    float*  Wbuf   = (float*)ws;    ws += (size_t)NW*sizeof(float);
    float*  ddbuf  = (float*)ws;    ws += (size_t)NS*DD*sizeof(float);
    float*  wmat   = (float*)ws;    ws += (size_t)NS*DD*sizeof(float);

    pass1_kernel<<<NBLK, NTHR, 0, stream>>>(samples, last_point, emb,
                                            cells, coefs, ddbuf, chunk_sum,
                                            Wbuf);
    scan_kernel<<<DD, 64, 0, stream>>>(chunk_sum, offs);
    w_kernel<<<NBLK, NTHR, 0, stream>>>(ddbuf, offs, wmat);
    wacc_kernel<<<NACC, 256, 0, stream>>>(cells, coefs, wmat, Wbuf);
    final_kernel<<<NH*3, 256, 0, stream>>>(emb, Wbuf, out);
}